// Round 1
// baseline (1327.646 us; speedup 1.0000x reference)
//
#include <hip/hip_runtime.h>

#define NN 100000
#define DD 128
#define RESC 0.2f
#define EPSL 1e-5f

// ---------------------------------------------------------------- helpers
static __device__ __forceinline__ float f4c(const float4& v, int i) {
  switch (i & 3) { case 0: return v.x; case 1: return v.y; case 2: return v.z; default: return v.w; }
}

// ---------------------------------------------------------------- degree count
__global__ __launch_bounds__(256) void k_count(const int* __restrict__ src,
                                               const int* __restrict__ dst,
                                               int* __restrict__ dego,
                                               int* __restrict__ degi, int E) {
  int i = blockIdx.x * 256 + threadIdx.x;
  if (i < E) {
    atomicAdd(&dego[src[i]], 1);
    atomicAdd(&degi[dst[i]], 1);
  }
}

// ---------------------------------------------------------------- exclusive scan of deg_in -> row_ptr (single block)
__global__ __launch_bounds__(1024) void k_scan(const int* __restrict__ degi,
                                               int* __restrict__ rowp) {
  __shared__ int part[1024];
  const int t = threadIdx.x;
  const int chunk = (NN + 1023) >> 10;  // 98
  const int lo = t * chunk;
  const int hi = min(lo + chunk, NN);
  int s = 0;
  for (int i = lo; i < hi; ++i) s += degi[i];
  part[t] = s;
  __syncthreads();
  // Hillis-Steele inclusive scan over 1024 partials
  for (int off = 1; off < 1024; off <<= 1) {
    int add = (t >= off) ? part[t - off] : 0;
    __syncthreads();
    part[t] += add;
    __syncthreads();
  }
  int run = (t == 0) ? 0 : part[t - 1];
  for (int i = lo; i < hi; ++i) { rowp[i] = run; run += degi[i]; }
  if (t == 1023) rowp[NN] = run;
}

// ---------------------------------------------------------------- rsqrt(deg), cursor init
__global__ __launch_bounds__(256) void k_prep(const int* __restrict__ dego,
                                              const int* __restrict__ degi,
                                              const int* __restrict__ rowp,
                                              float* __restrict__ rsq_o,
                                              float* __restrict__ rsq_i,
                                              int* __restrict__ curs) {
  int i = blockIdx.x * 256 + threadIdx.x;
  if (i < NN) {
    rsq_o[i] = rsqrtf((float)max(dego[i], 1));
    rsq_i[i] = rsqrtf((float)max(degi[i], 1));
    curs[i] = rowp[i];
  }
}

// ---------------------------------------------------------------- CSR fill (col indices grouped by dst)
__global__ __launch_bounds__(256) void k_fill(const int* __restrict__ src,
                                              const int* __restrict__ dst,
                                              int* __restrict__ curs,
                                              int* __restrict__ colx, int E) {
  int i = blockIdx.x * 256 + threadIdx.x;
  if (i < E) {
    int d = dst[i];
    int pos = atomicAdd(&curs[d], 1);
    colx[pos] = src[i];
  }
}

// ---------------------------------------------------------------- GEMM: out[r][j] = sum_k pre(in[r][k]) * W[k][j]
// pre = (LN ? relu(LayerNorm(x))*rsq_o : x*rsq_o)
// block: 256 threads, 64 rows x 128 cols; thread tile 4 rows x 8 cols.
#define SXLD 132  // padded leading dim for sX (breaks 4-way bank alias on row-strided reads)
template <bool LN>
__global__ __launch_bounds__(256) void k_gemm(const float* __restrict__ in,
                                              const float* __restrict__ W,
                                              const float* __restrict__ rsq_o,
                                              const float* __restrict__ g,
                                              const float* __restrict__ bb,
                                              float* __restrict__ out) {
  extern __shared__ float lds[];
  float* sW = lds;               // [128][128]
  float* sX = lds + 128 * 128;   // [64][SXLD]
  const int tid = threadIdx.x;
  const int row0 = blockIdx.x * 64;

  // stage W (16384 floats, 16 x float4 per thread)
#pragma unroll
  for (int i = 0; i < 16; ++i) {
    int idx = i * 1024 + tid * 4;
    *(float4*)(sW + idx) = *(const float4*)(W + idx);
  }
  // stage X (8192 floats)
#pragma unroll
  for (int i = 0; i < 8; ++i) {
    int linear = i * 1024 + tid * 4;
    int r = linear >> 7, k = linear & 127;
    int grow = row0 + r;
    float4 v;
    if (grow < NN) {
      v = *(const float4*)(in + (size_t)grow * DD + k);
      if (!LN) {
        float s = rsq_o[grow];
        v.x *= s; v.y *= s; v.z *= s; v.w *= s;
      }
    } else {
      v.x = v.y = v.z = v.w = 0.f;
    }
    *(float4*)(sX + r * SXLD + k) = v;
  }
  __syncthreads();

  if (LN) {
    // wave-per-row LayerNorm + relu + deg scale, in LDS
    const int wv = tid >> 6, ln = tid & 63;
    for (int rr = wv; rr < 64; rr += 4) {
      float x0 = sX[rr * SXLD + ln];
      float x1 = sX[rr * SXLD + 64 + ln];
      float s = x0 + x1, q = x0 * x0 + x1 * x1;
#pragma unroll
      for (int o = 32; o; o >>= 1) { s += __shfl_xor(s, o); q += __shfl_xor(q, o); }
      float mu = s * (1.f / 128.f);
      float var = q * (1.f / 128.f) - mu * mu;
      float rs = rsqrtf(var + EPSL);
      int grow = row0 + rr;
      float sc = (grow < NN) ? rsq_o[grow] : 0.f;
      float y0 = fmaxf((x0 - mu) * rs * g[ln] + bb[ln], 0.f) * sc;
      float y1 = fmaxf((x1 - mu) * rs * g[64 + ln] + bb[64 + ln], 0.f) * sc;
      sX[rr * SXLD + ln] = y0;
      sX[rr * SXLD + 64 + ln] = y1;
    }
    __syncthreads();
  }

  const int colg = tid & 15;   // 16 col groups of 8
  const int rowg = tid >> 4;   // 16 row groups of 4
  const int j0 = colg * 8, r0 = rowg * 4;
  float acc[4][8];
#pragma unroll
  for (int a = 0; a < 4; ++a)
#pragma unroll
    for (int b = 0; b < 8; ++b) acc[a][b] = 0.f;

  for (int k = 0; k < 128; k += 4) {
    float4 xv[4];
#pragma unroll
    for (int ri = 0; ri < 4; ++ri) xv[ri] = *(const float4*)(sX + (r0 + ri) * SXLD + k);
#pragma unroll
    for (int dk = 0; dk < 4; ++dk) {
      float4 wa = *(const float4*)(sW + (k + dk) * 128 + j0);
      float4 wb = *(const float4*)(sW + (k + dk) * 128 + j0 + 4);
#pragma unroll
      for (int ri = 0; ri < 4; ++ri) {
        float xx = f4c(xv[ri], dk);
        acc[ri][0] += xx * wa.x; acc[ri][1] += xx * wa.y;
        acc[ri][2] += xx * wa.z; acc[ri][3] += xx * wa.w;
        acc[ri][4] += xx * wb.x; acc[ri][5] += xx * wb.y;
        acc[ri][6] += xx * wb.z; acc[ri][7] += xx * wb.w;
      }
    }
  }

#pragma unroll
  for (int ri = 0; ri < 4; ++ri) {
    int grow = row0 + r0 + ri;
    if (grow < NN) {
      float4 o0, o1;
      o0.x = acc[ri][0]; o0.y = acc[ri][1]; o0.z = acc[ri][2]; o0.w = acc[ri][3];
      o1.x = acc[ri][4]; o1.y = acc[ri][5]; o1.z = acc[ri][6]; o1.w = acc[ri][7];
      *(float4*)(out + (size_t)grow * DD + j0) = o0;
      *(float4*)(out + (size_t)grow * DD + j0 + 4) = o1;
    }
  }
}

// ---------------------------------------------------------------- gather: out[n] = (sum_{e in row n} xw[col[e]]) * rsq_i[n] + bias + RESC*resid[n]
// one wave per node; lane holds float2 (64*8B = full 512B row)
__global__ __launch_bounds__(256) void k_gather(const float* __restrict__ xw,
                                                const int* __restrict__ colx,
                                                const int* __restrict__ rowp,
                                                const float* __restrict__ rsq_i,
                                                const float* __restrict__ bias,
                                                const float* __restrict__ resid,
                                                float* __restrict__ out) {
  const int wave = (blockIdx.x * 256 + threadIdx.x) >> 6;
  const int lane = threadIdx.x & 63;
  if (wave >= NN) return;
  const int beg = rowp[wave], end = rowp[wave + 1];
  float a0x = 0.f, a0y = 0.f, a1x = 0.f, a1y = 0.f;
  int e = beg;
  for (; e + 1 < end; e += 2) {
    int c0 = colx[e], c1 = colx[e + 1];
    float2 v0 = *(const float2*)(xw + (size_t)c0 * DD + lane * 2);
    float2 v1 = *(const float2*)(xw + (size_t)c1 * DD + lane * 2);
    a0x += v0.x; a0y += v0.y;
    a1x += v1.x; a1y += v1.y;
  }
  if (e < end) {
    int c = colx[e];
    float2 v = *(const float2*)(xw + (size_t)c * DD + lane * 2);
    a0x += v.x; a0y += v.y;
  }
  const float r = rsq_i[wave];
  float2 bbv = *(const float2*)(bias + lane * 2);
  float2 rf = *(const float2*)(resid + (size_t)wave * DD + lane * 2);
  float2 o;
  o.x = (a0x + a1x) * r + bbv.x + RESC * rf.x;
  o.y = (a0y + a1y) * r + bbv.y + RESC * rf.y;
  *(float2*)(out + (size_t)wave * DD + lane * 2) = o;
}

// ---------------------------------------------------------------- launcher
extern "C" void kernel_launch(void* const* d_in, const int* in_sizes, int n_in,
                              void* d_out, int out_size, void* d_ws, size_t ws_size,
                              hipStream_t stream) {
  const int* src = (const int*)d_in[0];
  const int* dst = (const int*)d_in[1];
  const float* in_feat = (const float*)d_in[2];
  const float* W1 = (const float*)d_in[3];
  const float* b1 = (const float*)d_in[4];
  const float* W2 = (const float*)d_in[5];
  const float* b2 = (const float*)d_in[6];
  const float* g1 = (const float*)d_in[7];
  const float* lb1 = (const float*)d_in[8];
  const float* g2 = (const float*)d_in[9];
  const float* lb2 = (const float*)d_in[10];
  const int E = in_sizes[0];

  char* p = (char*)d_ws;
  auto alloc = [&](size_t bytes) {
    char* q = p;
    p += (bytes + 255) & ~(size_t)255;
    return q;
  };
  float* xw    = (float*)alloc((size_t)NN * DD * 4);
  float* hb    = (float*)alloc((size_t)NN * DD * 4);
  float* rsq_o = (float*)alloc((size_t)NN * 4);
  float* rsq_i = (float*)alloc((size_t)NN * 4);
  int*   dego  = (int*)alloc((size_t)NN * 4);
  int*   degi  = (int*)alloc((size_t)NN * 4);
  int*   rowp  = (int*)alloc((size_t)(NN + 1) * 4);
  int*   curs  = (int*)alloc((size_t)NN * 4);
  int*   colx  = (int*)alloc((size_t)E * 4);
  if ((size_t)(p - (char*)d_ws) > ws_size) return;  // ws too small -> will surface as validation failure

  hipMemsetAsync(dego, 0, (size_t)NN * 4, stream);
  hipMemsetAsync(degi, 0, (size_t)NN * 4, stream);

  const int eb = (E + 255) / 256;
  k_count<<<eb, 256, 0, stream>>>(src, dst, dego, degi, E);
  k_scan<<<1, 1024, 0, stream>>>(degi, rowp);
  k_prep<<<(NN + 255) / 256, 256, 0, stream>>>(dego, degi, rowp, rsq_o, rsq_i, curs);
  k_fill<<<eb, 256, 0, stream>>>(src, dst, curs, colx, E);

  const int gblk = (NN + 63) / 64;
  const size_t ldsb = (size_t)(128 * 128 + 64 * SXLD) * sizeof(float);
  const int agblk = (NN + 3) / 4;

  // conv1
  k_gemm<false><<<gblk, 256, ldsb, stream>>>(in_feat, W1, rsq_o, nullptr, nullptr, xw);
  k_gather<<<agblk, 256, 0, stream>>>(xw, colx, rowp, rsq_i, b1, in_feat, hb);
  // conv2 (LN1 + relu fused)
  k_gemm<true><<<gblk, 256, ldsb, stream>>>(hb, W2, rsq_o, g1, lb1, xw);
  k_gather<<<agblk, 256, 0, stream>>>(xw, colx, rowp, rsq_i, b2, in_feat, hb);
  // conv3 (LN2 + relu fused)
  k_gemm<true><<<gblk, 256, ldsb, stream>>>(hb, W2, rsq_o, g2, lb2, xw);
  k_gather<<<agblk, 256, 0, stream>>>(xw, colx, rowp, rsq_i, b2, in_feat, (float*)d_out);
}

// Round 2
// 1042.337 us; speedup vs baseline: 1.2737x; 1.2737x over previous
//
#include <hip/hip_runtime.h>

#define NN 100000
#define DD 128
#define RESC 0.2f
#define EPSL 1e-5f
#define SCHUNK 1024
#define SBLK ((NN + SCHUNK - 1) / SCHUNK)  // 98

// ---------------------------------------------------------------- helpers
static __device__ __forceinline__ float f4c(const float4& v, int i) {
  switch (i & 3) { case 0: return v.x; case 1: return v.y; case 2: return v.z; default: return v.w; }
}

// ---------------------------------------------------------------- degree count
__global__ __launch_bounds__(256) void k_count(const int* __restrict__ src,
                                               const int* __restrict__ dst,
                                               int* __restrict__ dego,
                                               int* __restrict__ degi, int E) {
  int i = blockIdx.x * 256 + threadIdx.x;
  if (i < E) {
    atomicAdd(&dego[src[i]], 1);
    atomicAdd(&degi[dst[i]], 1);
  }
}

// ---------------------------------------------------------------- scan tier 1: per-1024-chunk sums
__global__ __launch_bounds__(256) void k_scan1(const int* __restrict__ degi,
                                               int* __restrict__ bsum) {
  __shared__ int red[256];
  const int t = threadIdx.x;
  const int base = blockIdx.x * SCHUNK;
  int s = 0;
#pragma unroll
  for (int j = 0; j < 4; ++j) {
    int i = base + j * 256 + t;
    if (i < NN) s += degi[i];
  }
  red[t] = s;
  __syncthreads();
  for (int off = 128; off; off >>= 1) {
    if (t < off) red[t] += red[t + off];
    __syncthreads();
  }
  if (t == 0) bsum[blockIdx.x] = red[0];
}

// ---------------------------------------------------------------- scan tier 2: exclusive scan of 98 partials
__global__ __launch_bounds__(128) void k_scan2(const int* __restrict__ bsum,
                                               int* __restrict__ bpre) {
  __shared__ int sh[128];
  const int t = threadIdx.x;
  int v = (t < SBLK) ? bsum[t] : 0;
  sh[t] = v;
  __syncthreads();
  for (int off = 1; off < 128; off <<= 1) {
    int add = (t >= off) ? sh[t - off] : 0;
    __syncthreads();
    sh[t] += add;
    __syncthreads();
  }
  if (t < SBLK) bpre[t] = (t == 0) ? 0 : sh[t - 1];
}

// ---------------------------------------------------------------- scan tier 3: local scan + rowp/curs/rsq (prep fused)
__global__ __launch_bounds__(256) void k_scan3(const int* __restrict__ degi,
                                               const int* __restrict__ dego,
                                               const int* __restrict__ bpre,
                                               int* __restrict__ rowp,
                                               int* __restrict__ curs,
                                               float* __restrict__ rsq_o,
                                               float* __restrict__ rsq_i, int E) {
  __shared__ int sh[256];
  const int t = threadIdx.x;
  const int i0 = blockIdx.x * SCHUNK + t * 4;
  int4 d = {0, 0, 0, 0};
  if (i0 + 3 < NN) {
    d = *(const int4*)(degi + i0);
  } else if (i0 < NN) {
    d.x = degi[i0];
    d.y = (i0 + 1 < NN) ? degi[i0 + 1] : 0;
    d.z = (i0 + 2 < NN) ? degi[i0 + 2] : 0;
    d.w = (i0 + 3 < NN) ? degi[i0 + 3] : 0;
  }
  const int s1 = d.x, s2 = s1 + d.y, s3 = s2 + d.z, s4 = s3 + d.w;
  sh[t] = s4;
  __syncthreads();
  for (int off = 1; off < 256; off <<= 1) {
    int add = (t >= off) ? sh[t - off] : 0;
    __syncthreads();
    sh[t] += add;
    __syncthreads();
  }
  const int r0 = bpre[blockIdx.x] + ((t == 0) ? 0 : sh[t - 1]);
  const int rp[4] = {r0, r0 + s1, r0 + s2, r0 + s3};
  const int dd[4] = {d.x, d.y, d.z, d.w};
#pragma unroll
  for (int j = 0; j < 4; ++j) {
    int i = i0 + j;
    if (i < NN) {
      rowp[i] = rp[j];
      curs[i] = rp[j];
      rsq_i[i] = rsqrtf((float)max(dd[j], 1));
      rsq_o[i] = rsqrtf((float)max(dego[i], 1));
    }
  }
  if (blockIdx.x == 0 && t == 0) rowp[NN] = E;
}

// ---------------------------------------------------------------- CSR fill (col indices grouped by dst)
__global__ __launch_bounds__(256) void k_fill(const int* __restrict__ src,
                                              const int* __restrict__ dst,
                                              int* __restrict__ curs,
                                              int* __restrict__ colx, int E) {
  int i = blockIdx.x * 256 + threadIdx.x;
  if (i < E) {
    int d = dst[i];
    int pos = atomicAdd(&curs[d], 1);
    colx[pos] = src[i];
  }
}

// ---------------------------------------------------------------- GEMM: out[r][j] = sum_k pre(in[r][k]) * W[k][j]
// 128x128 block tile, 256 threads, 8x8 thread tile (rows interleaved by 16).
#define SXLD 132
template <bool LN>
__global__ __launch_bounds__(256) void k_gemm(const float* __restrict__ in,
                                              const float* __restrict__ W,
                                              const float* __restrict__ rsq_o,
                                              const float* __restrict__ g,
                                              const float* __restrict__ bb,
                                              float* __restrict__ out) {
  extern __shared__ float lds[];
  float* sW = lds;               // [128][128]
  float* sX = lds + 128 * 128;   // [128][SXLD]
  const int tid = threadIdx.x;
  const int row0 = blockIdx.x * 128;

  // stage W (16384 floats)
#pragma unroll
  for (int i = 0; i < 16; ++i) {
    int idx = i * 1024 + tid * 4;
    *(float4*)(sW + idx) = *(const float4*)(W + idx);
  }
  // stage X (16384 floats)
#pragma unroll
  for (int i = 0; i < 16; ++i) {
    int linear = i * 1024 + tid * 4;
    int r = linear >> 7, k = linear & 127;
    int grow = row0 + r;
    float4 v;
    if (grow < NN) {
      v = *(const float4*)(in + (size_t)grow * DD + k);
      if (!LN) {
        float s = rsq_o[grow];
        v.x *= s; v.y *= s; v.z *= s; v.w *= s;
      }
    } else {
      v.x = v.y = v.z = v.w = 0.f;
    }
    *(float4*)(sX + r * SXLD + k) = v;
  }
  __syncthreads();

  if (LN) {
    const int wv = tid >> 6, ln = tid & 63;
    for (int rr = wv; rr < 128; rr += 4) {
      float x0 = sX[rr * SXLD + ln];
      float x1 = sX[rr * SXLD + 64 + ln];
      float s = x0 + x1, q = x0 * x0 + x1 * x1;
#pragma unroll
      for (int o = 32; o; o >>= 1) { s += __shfl_xor(s, o); q += __shfl_xor(q, o); }
      float mu = s * (1.f / 128.f);
      float var = q * (1.f / 128.f) - mu * mu;
      float rs = rsqrtf(var + EPSL);
      int grow = row0 + rr;
      float sc = (grow < NN) ? rsq_o[grow] : 0.f;
      float y0 = fmaxf((x0 - mu) * rs * g[ln] + bb[ln], 0.f) * sc;
      float y1 = fmaxf((x1 - mu) * rs * g[64 + ln] + bb[64 + ln], 0.f) * sc;
      sX[rr * SXLD + ln] = y0;
      sX[rr * SXLD + 64 + ln] = y1;
    }
    __syncthreads();
  }

  // thread tile: cols j0..j0+3 and 64+j0..+3; rows rowg+16*ri
  const int lane = tid & 63, wv = tid >> 6;
  const int colg = lane & 15;
  const int rowg = (lane >> 4) | (wv << 2);
  const int j0 = colg * 4;
  float4 acc0[8], acc1[8];
#pragma unroll
  for (int a = 0; a < 8; ++a) {
    acc0[a].x = acc0[a].y = acc0[a].z = acc0[a].w = 0.f;
    acc1[a].x = acc1[a].y = acc1[a].z = acc1[a].w = 0.f;
  }

  for (int k = 0; k < 128; k += 4) {
    float4 xv[8];
#pragma unroll
    for (int ri = 0; ri < 8; ++ri)
      xv[ri] = *(const float4*)(sX + (rowg + 16 * ri) * SXLD + k);
#pragma unroll
    for (int dk = 0; dk < 4; ++dk) {
      float4 wa = *(const float4*)(sW + (k + dk) * 128 + j0);
      float4 wb = *(const float4*)(sW + (k + dk) * 128 + 64 + j0);
#pragma unroll
      for (int ri = 0; ri < 8; ++ri) {
        float xx = f4c(xv[ri], dk);
        acc0[ri].x += xx * wa.x; acc0[ri].y += xx * wa.y;
        acc0[ri].z += xx * wa.z; acc0[ri].w += xx * wa.w;
        acc1[ri].x += xx * wb.x; acc1[ri].y += xx * wb.y;
        acc1[ri].z += xx * wb.z; acc1[ri].w += xx * wb.w;
      }
    }
  }

#pragma unroll
  for (int ri = 0; ri < 8; ++ri) {
    int grow = row0 + rowg + 16 * ri;
    if (grow < NN) {
      *(float4*)(out + (size_t)grow * DD + j0) = acc0[ri];
      *(float4*)(out + (size_t)grow * DD + 64 + j0) = acc1[ri];
    }
  }
}

// ---------------------------------------------------------------- gather: one wave per node, float4 lanes, 2 edges per step, x2 unroll
__global__ __launch_bounds__(256) void k_gather(const float* __restrict__ xw,
                                                const int* __restrict__ colx,
                                                const int* __restrict__ rowp,
                                                const float* __restrict__ rsq_i,
                                                const float* __restrict__ bias,
                                                const float* __restrict__ resid,
                                                float* __restrict__ out) {
  const int wave = (blockIdx.x * 256 + threadIdx.x) >> 6;
  const int lane = threadIdx.x & 63;
  const int half = lane >> 5;
  const int l32 = lane & 31;
  if (wave >= NN) return;
  const int beg = rowp[wave], end = rowp[wave + 1];
  float4 a0 = {0.f, 0.f, 0.f, 0.f}, a1 = {0.f, 0.f, 0.f, 0.f};
  int e = beg + half;
  for (; e + 2 < end; e += 4) {  // this half: edges e and e+2 (4 loads in flight per wave)
    int c0 = colx[e], c1 = colx[e + 2];
    float4 v0 = *(const float4*)(xw + (size_t)c0 * DD + l32 * 4);
    float4 v1 = *(const float4*)(xw + (size_t)c1 * DD + l32 * 4);
    a0.x += v0.x; a0.y += v0.y; a0.z += v0.z; a0.w += v0.w;
    a1.x += v1.x; a1.y += v1.y; a1.z += v1.z; a1.w += v1.w;
  }
  if (e < end) {
    int c = colx[e];
    float4 v = *(const float4*)(xw + (size_t)c * DD + l32 * 4);
    a0.x += v.x; a0.y += v.y; a0.z += v.z; a0.w += v.w;
  }
  a0.x += a1.x; a0.y += a1.y; a0.z += a1.z; a0.w += a1.w;
  a0.x += __shfl_xor(a0.x, 32);
  a0.y += __shfl_xor(a0.y, 32);
  a0.z += __shfl_xor(a0.z, 32);
  a0.w += __shfl_xor(a0.w, 32);
  if (half == 0) {
    const float r = rsq_i[wave];
    float4 bv = *(const float4*)(bias + l32 * 4);
    float4 rf = *(const float4*)(resid + (size_t)wave * DD + l32 * 4);
    float4 o;
    o.x = a0.x * r + bv.x + RESC * rf.x;
    o.y = a0.y * r + bv.y + RESC * rf.y;
    o.z = a0.z * r + bv.z + RESC * rf.z;
    o.w = a0.w * r + bv.w + RESC * rf.w;
    *(float4*)(out + (size_t)wave * DD + l32 * 4) = o;
  }
}

// ---------------------------------------------------------------- launcher
extern "C" void kernel_launch(void* const* d_in, const int* in_sizes, int n_in,
                              void* d_out, int out_size, void* d_ws, size_t ws_size,
                              hipStream_t stream) {
  const int* src = (const int*)d_in[0];
  const int* dst = (const int*)d_in[1];
  const float* in_feat = (const float*)d_in[2];
  const float* W1 = (const float*)d_in[3];
  const float* b1 = (const float*)d_in[4];
  const float* W2 = (const float*)d_in[5];
  const float* b2 = (const float*)d_in[6];
  const float* g1 = (const float*)d_in[7];
  const float* lb1 = (const float*)d_in[8];
  const float* g2 = (const float*)d_in[9];
  const float* lb2 = (const float*)d_in[10];
  const int E = in_sizes[0];

  char* p = (char*)d_ws;
  auto alloc = [&](size_t bytes) {
    char* q = p;
    p += (bytes + 255) & ~(size_t)255;
    return q;
  };
  float* xw    = (float*)alloc((size_t)NN * DD * 4);
  float* hb    = (float*)alloc((size_t)NN * DD * 4);
  float* rsq_o = (float*)alloc((size_t)NN * 4);
  float* rsq_i = (float*)alloc((size_t)NN * 4);
  int*   dego  = (int*)alloc((size_t)NN * 4);
  int*   degi  = (int*)alloc((size_t)NN * 4);
  int*   rowp  = (int*)alloc((size_t)(NN + 1) * 4);
  int*   curs  = (int*)alloc((size_t)NN * 4);
  int*   colx  = (int*)alloc((size_t)E * 4);
  int*   bsum  = (int*)alloc((size_t)SBLK * 4);
  int*   bpre  = (int*)alloc((size_t)SBLK * 4);
  if ((size_t)(p - (char*)d_ws) > ws_size) return;

  hipMemsetAsync(dego, 0, (size_t)NN * 4, stream);
  hipMemsetAsync(degi, 0, (size_t)NN * 4, stream);

  const int eb = (E + 255) / 256;
  k_count<<<eb, 256, 0, stream>>>(src, dst, dego, degi, E);
  k_scan1<<<SBLK, 256, 0, stream>>>(degi, bsum);
  k_scan2<<<1, 128, 0, stream>>>(bsum, bpre);
  k_scan3<<<SBLK, 256, 0, stream>>>(degi, dego, bpre, rowp, curs, rsq_o, rsq_i, E);
  k_fill<<<eb, 256, 0, stream>>>(src, dst, curs, colx, E);

  const int gblk = (NN + 127) / 128;
  const size_t ldsb = (size_t)(128 * 128 + 128 * SXLD) * sizeof(float);
  const int agblk = (NN * 64 + 255) / 256;

  // conv1
  k_gemm<false><<<gblk, 256, ldsb, stream>>>(in_feat, W1, rsq_o, nullptr, nullptr, xw);
  k_gather<<<agblk, 256, 0, stream>>>(xw, colx, rowp, rsq_i, b1, in_feat, hb);
  // conv2 (LN1 + relu fused)
  k_gemm<true><<<gblk, 256, ldsb, stream>>>(hb, W2, rsq_o, g1, lb1, xw);
  k_gather<<<agblk, 256, 0, stream>>>(xw, colx, rowp, rsq_i, b2, in_feat, hb);
  // conv3 (LN2 + relu fused)
  k_gemm<true><<<gblk, 256, ldsb, stream>>>(hb, W2, rsq_o, g2, lb2, xw);
  k_gather<<<agblk, 256, 0, stream>>>(xw, colx, rowp, rsq_i, b2, in_feat, (float*)d_out);
}

// Round 3
// 926.709 us; speedup vs baseline: 1.4326x; 1.1248x over previous
//
#include <hip/hip_runtime.h>

#define NN 100000
#define DD 128
#define RESC 0.2f
#define EPSL 1e-5f
#define SCHUNK 1024
#define SBLK ((NN + SCHUNK - 1) / SCHUNK)  // 98

// ---------------------------------------------------------------- helpers
static __device__ __forceinline__ float f4c(const float4& v, int i) {
  switch (i & 3) { case 0: return v.x; case 1: return v.y; case 2: return v.z; default: return v.w; }
}

// ---------------------------------------------------------------- degree count
__global__ __launch_bounds__(256) void k_count(const int* __restrict__ src,
                                               const int* __restrict__ dst,
                                               int* __restrict__ dego,
                                               int* __restrict__ degi, int E) {
  int i = blockIdx.x * 256 + threadIdx.x;
  if (i < E) {
    atomicAdd(&dego[src[i]], 1);
    atomicAdd(&degi[dst[i]], 1);
  }
}

// ---------------------------------------------------------------- scan tier 1
__global__ __launch_bounds__(256) void k_scan1(const int* __restrict__ degi,
                                               int* __restrict__ bsum) {
  __shared__ int red[256];
  const int t = threadIdx.x;
  const int base = blockIdx.x * SCHUNK;
  int s = 0;
#pragma unroll
  for (int j = 0; j < 4; ++j) {
    int i = base + j * 256 + t;
    if (i < NN) s += degi[i];
  }
  red[t] = s;
  __syncthreads();
  for (int off = 128; off; off >>= 1) {
    if (t < off) red[t] += red[t + off];
    __syncthreads();
  }
  if (t == 0) bsum[blockIdx.x] = red[0];
}

// ---------------------------------------------------------------- scan tier 2
__global__ __launch_bounds__(128) void k_scan2(const int* __restrict__ bsum,
                                               int* __restrict__ bpre) {
  __shared__ int sh[128];
  const int t = threadIdx.x;
  int v = (t < SBLK) ? bsum[t] : 0;
  sh[t] = v;
  __syncthreads();
  for (int off = 1; off < 128; off <<= 1) {
    int add = (t >= off) ? sh[t - off] : 0;
    __syncthreads();
    sh[t] += add;
    __syncthreads();
  }
  if (t < SBLK) bpre[t] = (t == 0) ? 0 : sh[t - 1];
}

// ---------------------------------------------------------------- scan tier 3 + prep fused
__global__ __launch_bounds__(256) void k_scan3(const int* __restrict__ degi,
                                               const int* __restrict__ dego,
                                               const int* __restrict__ bpre,
                                               int* __restrict__ rowp,
                                               int* __restrict__ curs,
                                               float* __restrict__ rsq_o,
                                               float* __restrict__ rsq_i, int E) {
  __shared__ int sh[256];
  const int t = threadIdx.x;
  const int i0 = blockIdx.x * SCHUNK + t * 4;
  int4 d = {0, 0, 0, 0};
  if (i0 + 3 < NN) {
    d = *(const int4*)(degi + i0);
  } else if (i0 < NN) {
    d.x = degi[i0];
    d.y = (i0 + 1 < NN) ? degi[i0 + 1] : 0;
    d.z = (i0 + 2 < NN) ? degi[i0 + 2] : 0;
    d.w = (i0 + 3 < NN) ? degi[i0 + 3] : 0;
  }
  const int s1 = d.x, s2 = s1 + d.y, s3 = s2 + d.z, s4 = s3 + d.w;
  sh[t] = s4;
  __syncthreads();
  for (int off = 1; off < 256; off <<= 1) {
    int add = (t >= off) ? sh[t - off] : 0;
    __syncthreads();
    sh[t] += add;
    __syncthreads();
  }
  const int r0 = bpre[blockIdx.x] + ((t == 0) ? 0 : sh[t - 1]);
  const int rp[4] = {r0, r0 + s1, r0 + s2, r0 + s3};
  const int dd[4] = {d.x, d.y, d.z, d.w};
#pragma unroll
  for (int j = 0; j < 4; ++j) {
    int i = i0 + j;
    if (i < NN) {
      rowp[i] = rp[j];
      curs[i] = rp[j];
      rsq_i[i] = rsqrtf((float)max(dd[j], 1));
      rsq_o[i] = rsqrtf((float)max(dego[i], 1));
    }
  }
  if (blockIdx.x == 0 && t == 0) rowp[NN] = E;
}

// ---------------------------------------------------------------- CSR fill
__global__ __launch_bounds__(256) void k_fill(const int* __restrict__ src,
                                              const int* __restrict__ dst,
                                              int* __restrict__ curs,
                                              int* __restrict__ colx, int E) {
  int i = blockIdx.x * 256 + threadIdx.x;
  if (i < E) {
    int d = dst[i];
    int pos = atomicAdd(&curs[d], 1);
    colx[pos] = src[i];
  }
}

// ---------------------------------------------------------------- GEMM: out = stage(in) @ W
// 128x128 block tile, 512 threads (8 waves/CU), 8 rows x 4 cols per thread.
// SCALE: multiply rows by rsq_o during staging (conv1 only; conv2/3 input is pre-activated).
#define SXLD 132
template <bool SCALE>
__global__ __launch_bounds__(512, 2) void k_gemm(const float* __restrict__ in,
                                                 const float* __restrict__ W,
                                                 const float* __restrict__ rsq_o,
                                                 float* __restrict__ out) {
  extern __shared__ float lds[];
  float* sW = lds;               // [128][128]
  float* sX = lds + 128 * 128;   // [128][SXLD]
  const int tid = threadIdx.x;
  const int row0 = blockIdx.x * 128;

  // stage W (16384 floats, 8 x float4 per thread)
#pragma unroll
  for (int i = 0; i < 8; ++i) {
    int idx = i * 2048 + tid * 4;
    *(float4*)(sW + idx) = *(const float4*)(W + idx);
  }
  // stage X (16384 floats)
#pragma unroll
  for (int i = 0; i < 8; ++i) {
    int linear = i * 2048 + tid * 4;
    int r = linear >> 7, k = linear & 127;
    int grow = row0 + r;
    float4 v;
    if (grow < NN) {
      v = *(const float4*)(in + (size_t)grow * DD + k);
      if (SCALE) {
        float s = rsq_o[grow];
        v.x *= s; v.y *= s; v.z *= s; v.w *= s;
      }
    } else {
      v.x = v.y = v.z = v.w = 0.f;
    }
    *(float4*)(sX + r * SXLD + k) = v;
  }
  __syncthreads();

  // thread tile: 8 rows (rowg + 16*ri) x 4 cols (j0..j0+3)
  const int colg = tid & 31;
  const int rowg = tid >> 5;  // 0..15
  const int j0 = colg * 4;
  float4 acc[8];
#pragma unroll
  for (int a = 0; a < 8; ++a) acc[a].x = acc[a].y = acc[a].z = acc[a].w = 0.f;

  for (int k = 0; k < 128; k += 4) {
    float4 xv[8];
#pragma unroll
    for (int ri = 0; ri < 8; ++ri)
      xv[ri] = *(const float4*)(sX + (rowg + 16 * ri) * SXLD + k);
#pragma unroll
    for (int dk = 0; dk < 4; ++dk) {
      float4 wa = *(const float4*)(sW + (k + dk) * 128 + j0);
#pragma unroll
      for (int ri = 0; ri < 8; ++ri) {
        float xx = f4c(xv[ri], dk);
        acc[ri].x += xx * wa.x; acc[ri].y += xx * wa.y;
        acc[ri].z += xx * wa.z; acc[ri].w += xx * wa.w;
      }
    }
  }

#pragma unroll
  for (int ri = 0; ri < 8; ++ri) {
    int grow = row0 + rowg + 16 * ri;
    if (grow < NN) *(float4*)(out + (size_t)grow * DD + j0) = acc[ri];
  }
}

// ---------------------------------------------------------------- gather
// out[n] = h = (sum_e xw[col[e]])*rsq_i + bias + RESC*resid
// PRE: out = relu(LayerNorm(h))*rsq_o  (pre-activated input for the next conv)
template <bool PRE>
__global__ __launch_bounds__(256) void k_gather(const float* __restrict__ xw,
                                                const int* __restrict__ colx,
                                                const int* __restrict__ rowp,
                                                const float* __restrict__ rsq_i,
                                                const float* __restrict__ bias,
                                                const float* __restrict__ resid,
                                                const float* __restrict__ rsq_o,
                                                const float* __restrict__ g,
                                                const float* __restrict__ bb,
                                                float* __restrict__ out) {
  const int wave = (blockIdx.x * 256 + threadIdx.x) >> 6;
  const int lane = threadIdx.x & 63;
  const int half = lane >> 5;
  const int l32 = lane & 31;
  if (wave >= NN) return;
  const int beg = rowp[wave], end = rowp[wave + 1];
  float4 a0 = {0.f, 0.f, 0.f, 0.f}, a1 = {0.f, 0.f, 0.f, 0.f};
  int e = beg + half;
  for (; e + 2 < end; e += 4) {
    int c0 = colx[e], c1 = colx[e + 2];
    float4 v0 = *(const float4*)(xw + (size_t)c0 * DD + l32 * 4);
    float4 v1 = *(const float4*)(xw + (size_t)c1 * DD + l32 * 4);
    a0.x += v0.x; a0.y += v0.y; a0.z += v0.z; a0.w += v0.w;
    a1.x += v1.x; a1.y += v1.y; a1.z += v1.z; a1.w += v1.w;
  }
  if (e < end) {
    int c = colx[e];
    float4 v = *(const float4*)(xw + (size_t)c * DD + l32 * 4);
    a0.x += v.x; a0.y += v.y; a0.z += v.z; a0.w += v.w;
  }
  a0.x += a1.x; a0.y += a1.y; a0.z += a1.z; a0.w += a1.w;
  a0.x += __shfl_xor(a0.x, 32);
  a0.y += __shfl_xor(a0.y, 32);
  a0.z += __shfl_xor(a0.z, 32);
  a0.w += __shfl_xor(a0.w, 32);

  const float r = rsq_i[wave];
  float4 bv = *(const float4*)(bias + l32 * 4);
  float4 rf = *(const float4*)(resid + (size_t)wave * DD + l32 * 4);
  float4 o;
  o.x = a0.x * r + bv.x + RESC * rf.x;
  o.y = a0.y * r + bv.y + RESC * rf.y;
  o.z = a0.z * r + bv.z + RESC * rf.z;
  o.w = a0.w * r + bv.w + RESC * rf.w;

  if (PRE) {
    // LayerNorm over the 128-dim row (distributed as 32 lanes x 4 within each half)
    float s = o.x + o.y + o.z + o.w;
    float q = o.x * o.x + o.y * o.y + o.z * o.z + o.w * o.w;
#pragma unroll
    for (int off = 1; off < 32; off <<= 1) {
      s += __shfl_xor(s, off);
      q += __shfl_xor(q, off);
    }
    float mu = s * (1.f / 128.f);
    float var = q * (1.f / 128.f) - mu * mu;
    float rs = rsqrtf(var + EPSL);
    float sc = rsq_o[wave];
    float4 gv = *(const float4*)(g + l32 * 4);
    float4 lv = *(const float4*)(bb + l32 * 4);
    o.x = fmaxf((o.x - mu) * rs * gv.x + lv.x, 0.f) * sc;
    o.y = fmaxf((o.y - mu) * rs * gv.y + lv.y, 0.f) * sc;
    o.z = fmaxf((o.z - mu) * rs * gv.z + lv.z, 0.f) * sc;
    o.w = fmaxf((o.w - mu) * rs * gv.w + lv.w, 0.f) * sc;
  }

  if (half == 0) *(float4*)(out + (size_t)wave * DD + l32 * 4) = o;
}

// ---------------------------------------------------------------- launcher
extern "C" void kernel_launch(void* const* d_in, const int* in_sizes, int n_in,
                              void* d_out, int out_size, void* d_ws, size_t ws_size,
                              hipStream_t stream) {
  const int* src = (const int*)d_in[0];
  const int* dst = (const int*)d_in[1];
  const float* in_feat = (const float*)d_in[2];
  const float* W1 = (const float*)d_in[3];
  const float* b1 = (const float*)d_in[4];
  const float* W2 = (const float*)d_in[5];
  const float* b2 = (const float*)d_in[6];
  const float* g1 = (const float*)d_in[7];
  const float* lb1 = (const float*)d_in[8];
  const float* g2 = (const float*)d_in[9];
  const float* lb2 = (const float*)d_in[10];
  const int E = in_sizes[0];

  char* p = (char*)d_ws;
  auto alloc = [&](size_t bytes) {
    char* q = p;
    p += (bytes + 255) & ~(size_t)255;
    return q;
  };
  float* xw    = (float*)alloc((size_t)NN * DD * 4);
  float* hb    = (float*)alloc((size_t)NN * DD * 4);
  float* rsq_o = (float*)alloc((size_t)NN * 4);
  float* rsq_i = (float*)alloc((size_t)NN * 4);
  int*   dego  = (int*)alloc((size_t)NN * 4);
  int*   degi  = (int*)alloc((size_t)NN * 4);
  int*   rowp  = (int*)alloc((size_t)(NN + 1) * 4);
  int*   curs  = (int*)alloc((size_t)NN * 4);
  int*   colx  = (int*)alloc((size_t)E * 4);
  int*   bsum  = (int*)alloc((size_t)SBLK * 4);
  int*   bpre  = (int*)alloc((size_t)SBLK * 4);
  if ((size_t)(p - (char*)d_ws) > ws_size) return;

  hipMemsetAsync(dego, 0, (size_t)NN * 4, stream);
  hipMemsetAsync(degi, 0, (size_t)NN * 4, stream);

  const int eb = (E + 255) / 256;
  k_count<<<eb, 256, 0, stream>>>(src, dst, dego, degi, E);
  k_scan1<<<SBLK, 256, 0, stream>>>(degi, bsum);
  k_scan2<<<1, 128, 0, stream>>>(bsum, bpre);
  k_scan3<<<SBLK, 256, 0, stream>>>(degi, dego, bpre, rowp, curs, rsq_o, rsq_i, E);
  k_fill<<<eb, 256, 0, stream>>>(src, dst, curs, colx, E);

  const int gblk = (NN + 127) / 128;
  const size_t ldsb = (size_t)(128 * 128 + 128 * SXLD) * sizeof(float);
  const int agblk = (NN * 64 + 255) / 256;

  // conv1: xw = (in_feat*rsq_o) @ W1 ; h1' = pre(A xw + b1 + 0.2 in_feat)
  k_gemm<true><<<gblk, 512, ldsb, stream>>>(in_feat, W1, rsq_o, xw);
  k_gather<true><<<agblk, 256, 0, stream>>>(xw, colx, rowp, rsq_i, b1, in_feat, rsq_o, g1, lb1, hb);
  // conv2
  k_gemm<false><<<gblk, 512, ldsb, stream>>>(hb, W2, rsq_o, xw);
  k_gather<true><<<agblk, 256, 0, stream>>>(xw, colx, rowp, rsq_i, b2, in_feat, rsq_o, g2, lb2, hb);
  // conv3 (final: raw h to d_out)
  k_gemm<false><<<gblk, 512, ldsb, stream>>>(hb, W2, rsq_o, xw);
  k_gather<false><<<agblk, 256, 0, stream>>>(xw, colx, rowp, rsq_i, b2, in_feat, rsq_o, nullptr, nullptr, (float*)d_out);
}

// Round 4
// 807.577 us; speedup vs baseline: 1.6440x; 1.1475x over previous
//
#include <hip/hip_runtime.h>

#define NN 100000
#define DD 128
#define RESC 0.2f
#define EPSL 1e-5f
#define BSH 10
#define NBKT ((NN + 1023) >> BSH)  // 98

// ---------------------------------------------------------------- helpers
static __device__ __forceinline__ float f4c(const float4& v, int i) {
  switch (i & 3) { case 0: return v.x; case 1: return v.y; case 2: return v.z; default: return v.w; }
}

// ---------------------------------------------------------------- hist: bucket sizes (LDS-aggregated) + dego atomics
__global__ __launch_bounds__(256) void k_hist(const int* __restrict__ src,
                                              const int* __restrict__ dst,
                                              int* __restrict__ dego,
                                              int* __restrict__ bsum, int E) {
  __shared__ int cnt[NBKT];
  const int t = threadIdx.x;
  if (t < NBKT) cnt[t] = 0;
  __syncthreads();
  const int base = blockIdx.x * 4096 + t * 16;
#pragma unroll
  for (int q = 0; q < 4; ++q) {
    int idx = base + q * 4;
    int sv[4], dv[4];
    if (idx + 3 < E) {
      *(int4*)sv = *(const int4*)(src + idx);
      *(int4*)dv = *(const int4*)(dst + idx);
#pragma unroll
      for (int k = 0; k < 4; ++k) {
        atomicAdd(&dego[sv[k]], 1);
        atomicAdd(&cnt[dv[k] >> BSH], 1);
      }
    } else {
      for (int k = 0; k < 4 && idx + k < E; ++k) {
        atomicAdd(&dego[src[idx + k]], 1);
        atomicAdd(&cnt[dst[idx + k] >> BSH], 1);
      }
    }
  }
  __syncthreads();
  if (t < NBKT && cnt[t]) atomicAdd(&bsum[t], cnt[t]);
}

// ---------------------------------------------------------------- scan of 98 bucket sizes -> bpre (+ working copy bcur)
__global__ __launch_bounds__(128) void k_scan2(const int* __restrict__ bsum,
                                               int* __restrict__ bpre,
                                               int* __restrict__ bcur) {
  __shared__ int sh[128];
  const int t = threadIdx.x;
  int v = (t < NBKT) ? bsum[t] : 0;
  sh[t] = v;
  __syncthreads();
  for (int off = 1; off < 128; off <<= 1) {
    int add = (t >= off) ? sh[t - off] : 0;
    __syncthreads();
    sh[t] += add;
    __syncthreads();
  }
  if (t < NBKT) {
    int e = (t == 0) ? 0 : sh[t - 1];
    bpre[t] = e;
    bcur[t] = e;
  }
}

// ---------------------------------------------------------------- rsq_o
__global__ __launch_bounds__(256) void k_prep(const int* __restrict__ dego,
                                              float* __restrict__ rsq_o) {
  int i = blockIdx.x * 256 + threadIdx.x;
  if (i < NN) rsq_o[i] = rsqrtf((float)max(dego[i], 1));
}

// ---------------------------------------------------------------- binA: bucket-sort (src,dst) pairs into gpairs
__global__ __launch_bounds__(256) void k_binA(const int* __restrict__ src,
                                              const int* __restrict__ dst,
                                              int* __restrict__ bcur,
                                              int2* __restrict__ gpairs, int E) {
  __shared__ int cnt[NBKT], cnt2[NBKT], gofs[NBKT];
  const int t = threadIdx.x;
  if (t < NBKT) { cnt[t] = 0; cnt2[t] = 0; }
  __syncthreads();
  const int base = blockIdx.x * 4096 + t * 16;
  int sv[16], dv[16];
#pragma unroll
  for (int q = 0; q < 4; ++q) {
    int idx = base + q * 4;
    if (idx + 3 < E) {
      *(int4*)(sv + q * 4) = *(const int4*)(src + idx);
      *(int4*)(dv + q * 4) = *(const int4*)(dst + idx);
    } else {
#pragma unroll
      for (int k = 0; k < 4; ++k) {
        sv[q * 4 + k] = (idx + k < E) ? src[idx + k] : 0;
        dv[q * 4 + k] = (idx + k < E) ? dst[idx + k] : -1;
      }
    }
  }
#pragma unroll
  for (int j = 0; j < 16; ++j)
    if (base + j < E) atomicAdd(&cnt[dv[j] >> BSH], 1);
  __syncthreads();
  if (t < NBKT && cnt[t]) gofs[t] = atomicAdd(&bcur[t], cnt[t]);
  __syncthreads();
#pragma unroll
  for (int j = 0; j < 16; ++j)
    if (base + j < E) {
      int b = dv[j] >> BSH;
      int p = gofs[b] + atomicAdd(&cnt2[b], 1);
      gpairs[p] = make_int2(sv[j], dv[j]);
    }
}

// ---------------------------------------------------------------- binB: per-bucket local CSR (degi, rowp, rsq_i, colx) via LDS
__global__ __launch_bounds__(256) void k_binB(const int2* __restrict__ gpairs,
                                              const int* __restrict__ bpre,
                                              const int* __restrict__ bsum,
                                              int* __restrict__ rowp,
                                              float* __restrict__ rsq_i,
                                              int* __restrict__ colx, int E) {
  __shared__ int hist[1024];
  __shared__ int part[256];
  const int b = blockIdx.x, t = threadIdx.x;
  const int node0 = b << BSH;
  const int ebase = bpre[b], ecnt = bsum[b];
  for (int j = t; j < 1024; j += 256) hist[j] = 0;
  __syncthreads();
  for (int i = t; i < ecnt; i += 256)
    atomicAdd(&hist[gpairs[ebase + i].y - node0], 1);
  __syncthreads();
  const int j0 = t * 4;
  const int h0 = hist[j0], h1 = hist[j0 + 1], h2 = hist[j0 + 2], h3 = hist[j0 + 3];
  part[t] = h0 + h1 + h2 + h3;
  __syncthreads();
  for (int off = 1; off < 256; off <<= 1) {
    int add = (t >= off) ? part[t - off] : 0;
    __syncthreads();
    part[t] += add;
    __syncthreads();
  }
  int run = ebase + ((t == 0) ? 0 : part[t - 1]);
  const int pos[4] = {run, run + h0, run + h0 + h1, run + h0 + h1 + h2};
  const int hh[4] = {h0, h1, h2, h3};
#pragma unroll
  for (int k = 0; k < 4; ++k) {
    int node = node0 + j0 + k;
    if (node < NN) {
      rowp[node] = pos[k];
      rsq_i[node] = rsqrtf((float)max(hh[k], 1));
    }
  }
  // reuse hist as global-position cursors
#pragma unroll
  for (int k = 0; k < 4; ++k) hist[j0 + k] = pos[k];
  __syncthreads();
  for (int i = t; i < ecnt; i += 256) {
    int2 pr = gpairs[ebase + i];
    int p = atomicAdd(&hist[pr.y - node0], 1);
    colx[p] = pr.x;
  }
  if (b == NBKT - 1 && t == 0) rowp[NN] = ebase + ecnt;
}

// ---------------------------------------------------------------- GEMM: out = stage(in) @ W
#define SXLD 132
template <bool SCALE>
__global__ __launch_bounds__(512, 2) void k_gemm(const float* __restrict__ in,
                                                 const float* __restrict__ W,
                                                 const float* __restrict__ rsq_o,
                                                 float* __restrict__ out) {
  extern __shared__ float lds[];
  float* sW = lds;               // [128][128]
  float* sX = lds + 128 * 128;   // [128][SXLD]
  const int tid = threadIdx.x;
  const int row0 = blockIdx.x * 128;

#pragma unroll
  for (int i = 0; i < 8; ++i) {
    int idx = i * 2048 + tid * 4;
    *(float4*)(sW + idx) = *(const float4*)(W + idx);
  }
#pragma unroll
  for (int i = 0; i < 8; ++i) {
    int linear = i * 2048 + tid * 4;
    int r = linear >> 7, k = linear & 127;
    int grow = row0 + r;
    float4 v;
    if (grow < NN) {
      v = *(const float4*)(in + (size_t)grow * DD + k);
      if (SCALE) {
        float s = rsq_o[grow];
        v.x *= s; v.y *= s; v.z *= s; v.w *= s;
      }
    } else {
      v.x = v.y = v.z = v.w = 0.f;
    }
    *(float4*)(sX + r * SXLD + k) = v;
  }
  __syncthreads();

  const int colg = tid & 31;
  const int rowg = tid >> 5;
  const int j0 = colg * 4;
  float4 acc[8];
#pragma unroll
  for (int a = 0; a < 8; ++a) acc[a].x = acc[a].y = acc[a].z = acc[a].w = 0.f;

  for (int k = 0; k < 128; k += 4) {
    float4 xv[8];
#pragma unroll
    for (int ri = 0; ri < 8; ++ri)
      xv[ri] = *(const float4*)(sX + (rowg + 16 * ri) * SXLD + k);
#pragma unroll
    for (int dk = 0; dk < 4; ++dk) {
      float4 wa = *(const float4*)(sW + (k + dk) * 128 + j0);
#pragma unroll
      for (int ri = 0; ri < 8; ++ri) {
        float xx = f4c(xv[ri], dk);
        acc[ri].x += xx * wa.x; acc[ri].y += xx * wa.y;
        acc[ri].z += xx * wa.z; acc[ri].w += xx * wa.w;
      }
    }
  }

#pragma unroll
  for (int ri = 0; ri < 8; ++ri) {
    int grow = row0 + rowg + 16 * ri;
    if (grow < NN) *(float4*)(out + (size_t)grow * DD + j0) = acc[ri];
  }
}

// ---------------------------------------------------------------- gather (4 edges in flight per half)
template <bool PRE>
__global__ __launch_bounds__(256) void k_gather(const float* __restrict__ xw,
                                                const int* __restrict__ colx,
                                                const int* __restrict__ rowp,
                                                const float* __restrict__ rsq_i,
                                                const float* __restrict__ bias,
                                                const float* __restrict__ resid,
                                                const float* __restrict__ rsq_o,
                                                const float* __restrict__ g,
                                                const float* __restrict__ bb,
                                                float* __restrict__ out) {
  const int wave = (blockIdx.x * 256 + threadIdx.x) >> 6;
  const int lane = threadIdx.x & 63;
  const int half = lane >> 5;
  const int l32 = lane & 31;
  if (wave >= NN) return;
  const int beg = rowp[wave], end = rowp[wave + 1];
  float4 a0 = {0, 0, 0, 0}, a1 = {0, 0, 0, 0}, a2 = {0, 0, 0, 0}, a3 = {0, 0, 0, 0};
  int e = beg + half;
  for (; e + 6 < end; e += 8) {
    int c0 = colx[e], c1 = colx[e + 2], c2 = colx[e + 4], c3 = colx[e + 6];
    float4 v0 = *(const float4*)(xw + (size_t)c0 * DD + l32 * 4);
    float4 v1 = *(const float4*)(xw + (size_t)c1 * DD + l32 * 4);
    float4 v2 = *(const float4*)(xw + (size_t)c2 * DD + l32 * 4);
    float4 v3 = *(const float4*)(xw + (size_t)c3 * DD + l32 * 4);
    a0.x += v0.x; a0.y += v0.y; a0.z += v0.z; a0.w += v0.w;
    a1.x += v1.x; a1.y += v1.y; a1.z += v1.z; a1.w += v1.w;
    a2.x += v2.x; a2.y += v2.y; a2.z += v2.z; a2.w += v2.w;
    a3.x += v3.x; a3.y += v3.y; a3.z += v3.z; a3.w += v3.w;
  }
  for (; e < end; e += 2) {
    int c = colx[e];
    float4 v = *(const float4*)(xw + (size_t)c * DD + l32 * 4);
    a0.x += v.x; a0.y += v.y; a0.z += v.z; a0.w += v.w;
  }
  a0.x += a1.x + a2.x + a3.x;
  a0.y += a1.y + a2.y + a3.y;
  a0.z += a1.z + a2.z + a3.z;
  a0.w += a1.w + a2.w + a3.w;
  a0.x += __shfl_xor(a0.x, 32);
  a0.y += __shfl_xor(a0.y, 32);
  a0.z += __shfl_xor(a0.z, 32);
  a0.w += __shfl_xor(a0.w, 32);

  const float r = rsq_i[wave];
  float4 bv = *(const float4*)(bias + l32 * 4);
  float4 rf = *(const float4*)(resid + (size_t)wave * DD + l32 * 4);
  float4 o;
  o.x = a0.x * r + bv.x + RESC * rf.x;
  o.y = a0.y * r + bv.y + RESC * rf.y;
  o.z = a0.z * r + bv.z + RESC * rf.z;
  o.w = a0.w * r + bv.w + RESC * rf.w;

  if (PRE) {
    float s = o.x + o.y + o.z + o.w;
    float q = o.x * o.x + o.y * o.y + o.z * o.z + o.w * o.w;
#pragma unroll
    for (int off = 1; off < 32; off <<= 1) {
      s += __shfl_xor(s, off);
      q += __shfl_xor(q, off);
    }
    float mu = s * (1.f / 128.f);
    float var = q * (1.f / 128.f) - mu * mu;
    float rs = rsqrtf(var + EPSL);
    float sc = rsq_o[wave];
    float4 gv = *(const float4*)(g + l32 * 4);
    float4 lv = *(const float4*)(bb + l32 * 4);
    o.x = fmaxf((o.x - mu) * rs * gv.x + lv.x, 0.f) * sc;
    o.y = fmaxf((o.y - mu) * rs * gv.y + lv.y, 0.f) * sc;
    o.z = fmaxf((o.z - mu) * rs * gv.z + lv.z, 0.f) * sc;
    o.w = fmaxf((o.w - mu) * rs * gv.w + lv.w, 0.f) * sc;
  }

  if (half == 0) *(float4*)(out + (size_t)wave * DD + l32 * 4) = o;
}

// ---------------------------------------------------------------- launcher
extern "C" void kernel_launch(void* const* d_in, const int* in_sizes, int n_in,
                              void* d_out, int out_size, void* d_ws, size_t ws_size,
                              hipStream_t stream) {
  const int* src = (const int*)d_in[0];
  const int* dst = (const int*)d_in[1];
  const float* in_feat = (const float*)d_in[2];
  const float* W1 = (const float*)d_in[3];
  const float* b1 = (const float*)d_in[4];
  const float* W2 = (const float*)d_in[5];
  const float* b2 = (const float*)d_in[6];
  const float* g1 = (const float*)d_in[7];
  const float* lb1 = (const float*)d_in[8];
  const float* g2 = (const float*)d_in[9];
  const float* lb2 = (const float*)d_in[10];
  const int E = in_sizes[0];

  char* p = (char*)d_ws;
  auto alloc = [&](size_t bytes) {
    char* q = p;
    p += (bytes + 255) & ~(size_t)255;
    return q;
  };
  float* xw    = (float*)alloc((size_t)NN * DD * 4);
  float* hb    = (float*)alloc((size_t)NN * DD * 4);
  float* rsq_o = (float*)alloc((size_t)NN * 4);
  float* rsq_i = (float*)alloc((size_t)NN * 4);
  int*   dego  = (int*)alloc((size_t)NN * 4);
  int*   rowp  = (int*)alloc((size_t)(NN + 1) * 4);
  int*   colx  = (int*)alloc((size_t)E * 4);
  int*   bsum  = (int*)alloc((size_t)NBKT * 4);
  int*   bpre  = (int*)alloc((size_t)NBKT * 4);
  int*   bcur  = (int*)alloc((size_t)NBKT * 4);
  if ((size_t)(p - (char*)d_ws) > ws_size) return;
  int2* gpairs = (int2*)xw;  // alias: consumed by k_binB before gemm1 writes xw

  hipMemsetAsync(dego, 0, (size_t)NN * 4, stream);
  hipMemsetAsync(bsum, 0, (size_t)NBKT * 4, stream);

  const int eb = (E + 4095) / 4096;
  k_hist<<<eb, 256, 0, stream>>>(src, dst, dego, bsum, E);
  k_scan2<<<1, 128, 0, stream>>>(bsum, bpre, bcur);
  k_prep<<<(NN + 255) / 256, 256, 0, stream>>>(dego, rsq_o);
  k_binA<<<eb, 256, 0, stream>>>(src, dst, bcur, gpairs, E);
  k_binB<<<NBKT, 256, 0, stream>>>(gpairs, bpre, bsum, rowp, rsq_i, colx, E);

  const int gblk = (NN + 127) / 128;
  const size_t ldsb = (size_t)(128 * 128 + 128 * SXLD) * sizeof(float);
  const int agblk = (NN * 64 + 255) / 256;

  // conv1
  k_gemm<true><<<gblk, 512, ldsb, stream>>>(in_feat, W1, rsq_o, xw);
  k_gather<true><<<agblk, 256, 0, stream>>>(xw, colx, rowp, rsq_i, b1, in_feat, rsq_o, g1, lb1, hb);
  // conv2
  k_gemm<false><<<gblk, 512, ldsb, stream>>>(hb, W2, rsq_o, xw);
  k_gather<true><<<agblk, 256, 0, stream>>>(xw, colx, rowp, rsq_i, b2, in_feat, rsq_o, g2, lb2, hb);
  // conv3
  k_gemm<false><<<gblk, 512, ldsb, stream>>>(hb, W2, rsq_o, xw);
  k_gather<false><<<agblk, 256, 0, stream>>>(xw, colx, rowp, rsq_i, b2, in_feat, rsq_o, nullptr, nullptr, (float*)d_out);
}

// Round 5
// 520.823 us; speedup vs baseline: 2.5491x; 1.5506x over previous
//
#include <hip/hip_runtime.h>

#define NN 100000
#define DD 128
#define RESC 0.2f
#define EPSL 1e-5f
#define BSH 10
#define NBKT ((NN + 1023) >> BSH)  // 98

typedef _Float16 f16;
typedef _Float16 f16x2 __attribute__((ext_vector_type(2)));
typedef _Float16 f16x4 __attribute__((ext_vector_type(4)));
typedef _Float16 f16x8 __attribute__((ext_vector_type(8)));
typedef float f32x16 __attribute__((ext_vector_type(16)));

// LDS swizzle: row-major [128][128] halves, 256 B rows; XOR 16B-slot by (row&15)
static __device__ __forceinline__ int swz(int r, int c_half) {
  return r * 256 + ((c_half * 2) ^ ((r & 15) << 4));
}

// ---------------------------------------------------------------- hist: bucket sizes (LDS-aggregated) + dego atomics
__global__ __launch_bounds__(256) void k_hist(const int* __restrict__ src,
                                              const int* __restrict__ dst,
                                              int* __restrict__ dego,
                                              int* __restrict__ bsum, int E) {
  __shared__ int cnt[NBKT];
  const int t = threadIdx.x;
  if (t < NBKT) cnt[t] = 0;
  __syncthreads();
  const int base = blockIdx.x * 4096 + t * 16;
#pragma unroll
  for (int q = 0; q < 4; ++q) {
    int idx = base + q * 4;
    int sv[4], dv[4];
    if (idx + 3 < E) {
      *(int4*)sv = *(const int4*)(src + idx);
      *(int4*)dv = *(const int4*)(dst + idx);
#pragma unroll
      for (int k = 0; k < 4; ++k) {
        atomicAdd(&dego[sv[k]], 1);
        atomicAdd(&cnt[dv[k] >> BSH], 1);
      }
    } else {
      for (int k = 0; k < 4 && idx + k < E; ++k) {
        atomicAdd(&dego[src[idx + k]], 1);
        atomicAdd(&cnt[dst[idx + k] >> BSH], 1);
      }
    }
  }
  __syncthreads();
  if (t < NBKT && cnt[t]) atomicAdd(&bsum[t], cnt[t]);
}

// ---------------------------------------------------------------- scan of 98 bucket sizes
__global__ __launch_bounds__(128) void k_scan2(const int* __restrict__ bsum,
                                               int* __restrict__ bpre,
                                               int* __restrict__ bcur) {
  __shared__ int sh[128];
  const int t = threadIdx.x;
  int v = (t < NBKT) ? bsum[t] : 0;
  sh[t] = v;
  __syncthreads();
  for (int off = 1; off < 128; off <<= 1) {
    int add = (t >= off) ? sh[t - off] : 0;
    __syncthreads();
    sh[t] += add;
    __syncthreads();
  }
  if (t < NBKT) {
    int e = (t == 0) ? 0 : sh[t - 1];
    bpre[t] = e;
    bcur[t] = e;
  }
}

// ---------------------------------------------------------------- rsq_o
__global__ __launch_bounds__(256) void k_prep(const int* __restrict__ dego,
                                              float* __restrict__ rsq_o) {
  int i = blockIdx.x * 256 + threadIdx.x;
  if (i < NN) rsq_o[i] = rsqrtf((float)max(dego[i], 1));
}

// ---------------------------------------------------------------- W -> Wt fp16 transpose (Wt[n][k] = W[k][n])
__global__ __launch_bounds__(256) void k_wprep(const float* __restrict__ W,
                                               f16* __restrict__ Wt) {
  int i = blockIdx.x * 256 + threadIdx.x;  // 16384
  int n = i >> 7, k = i & 127;
  Wt[(size_t)n * 128 + k] = (f16)W[(size_t)k * 128 + n];
}

// ---------------------------------------------------------------- binA: bucket-sort pairs
__global__ __launch_bounds__(256) void k_binA(const int* __restrict__ src,
                                              const int* __restrict__ dst,
                                              int* __restrict__ bcur,
                                              int2* __restrict__ gpairs, int E) {
  __shared__ int cnt[NBKT], cnt2[NBKT], gofs[NBKT];
  const int t = threadIdx.x;
  if (t < NBKT) { cnt[t] = 0; cnt2[t] = 0; }
  __syncthreads();
  const int base = blockIdx.x * 4096 + t * 16;
  int sv[16], dv[16];
#pragma unroll
  for (int q = 0; q < 4; ++q) {
    int idx = base + q * 4;
    if (idx + 3 < E) {
      *(int4*)(sv + q * 4) = *(const int4*)(src + idx);
      *(int4*)(dv + q * 4) = *(const int4*)(dst + idx);
    } else {
#pragma unroll
      for (int k = 0; k < 4; ++k) {
        sv[q * 4 + k] = (idx + k < E) ? src[idx + k] : 0;
        dv[q * 4 + k] = (idx + k < E) ? dst[idx + k] : -1;
      }
    }
  }
#pragma unroll
  for (int j = 0; j < 16; ++j)
    if (base + j < E) atomicAdd(&cnt[dv[j] >> BSH], 1);
  __syncthreads();
  if (t < NBKT && cnt[t]) gofs[t] = atomicAdd(&bcur[t], cnt[t]);
  __syncthreads();
#pragma unroll
  for (int j = 0; j < 16; ++j)
    if (base + j < E) {
      int b = dv[j] >> BSH;
      int p = gofs[b] + atomicAdd(&cnt2[b], 1);
      gpairs[p] = make_int2(sv[j], dv[j]);
    }
}

// ---------------------------------------------------------------- binB: per-bucket CSR build
__global__ __launch_bounds__(256) void k_binB(const int2* __restrict__ gpairs,
                                              const int* __restrict__ bpre,
                                              const int* __restrict__ bsum,
                                              int* __restrict__ rowp,
                                              float* __restrict__ rsq_i,
                                              int* __restrict__ colx, int E) {
  __shared__ int hist[1024];
  __shared__ int part[256];
  const int b = blockIdx.x, t = threadIdx.x;
  const int node0 = b << BSH;
  const int ebase = bpre[b], ecnt = bsum[b];
  for (int j = t; j < 1024; j += 256) hist[j] = 0;
  __syncthreads();
  for (int i = t; i < ecnt; i += 256)
    atomicAdd(&hist[gpairs[ebase + i].y - node0], 1);
  __syncthreads();
  const int j0 = t * 4;
  const int h0 = hist[j0], h1 = hist[j0 + 1], h2 = hist[j0 + 2], h3 = hist[j0 + 3];
  part[t] = h0 + h1 + h2 + h3;
  __syncthreads();
  for (int off = 1; off < 256; off <<= 1) {
    int add = (t >= off) ? part[t - off] : 0;
    __syncthreads();
    part[t] += add;
    __syncthreads();
  }
  int run = ebase + ((t == 0) ? 0 : part[t - 1]);
  const int pos[4] = {run, run + h0, run + h0 + h1, run + h0 + h1 + h2};
  const int hh[4] = {h0, h1, h2, h3};
#pragma unroll
  for (int k = 0; k < 4; ++k) {
    int node = node0 + j0 + k;
    if (node < NN) {
      rowp[node] = pos[k];
      rsq_i[node] = rsqrtf((float)max(hh[k], 1));
    }
  }
#pragma unroll
  for (int k = 0; k < 4; ++k) hist[j0 + k] = pos[k];
  __syncthreads();
  for (int i = t; i < ecnt; i += 256) {
    int2 pr = gpairs[ebase + i];
    int p = atomicAdd(&hist[pr.y - node0], 1);
    colx[p] = pr.x;
  }
  if (b == NBKT - 1 && t == 0) rowp[NN] = ebase + ecnt;
}

// ---------------------------------------------------------------- MFMA GEMM (fp16 in, fp16 out, fp32 accum)
// 128-row tile, 256 thr = 4 waves; wave w owns rows w*32..w*32+31, all 128 cols.
// v_mfma_f32_32x32x16_f16: A m=lane&31, k=(lane>>5)*8+j ; B n=lane&31, same k ;
// C col=lane&31, row=(reg&3)+8*(reg>>2)+4*(lane>>5)   [learn_hip m74/m101]
template <bool SCALE>  // SCALE: input fp32, multiply by rsq_o during staging
__global__ __launch_bounds__(256, 2) void k_gemm16(const void* __restrict__ inp,
                                                   const f16* __restrict__ Wt,
                                                   const float* __restrict__ rsq_o,
                                                   f16* __restrict__ out) {
  extern __shared__ char smem[];  // 64 KB: sX [0,32K), sW [32K,64K)
  char* sX = smem;
  char* sW = smem + 32768;
  const int tid = threadIdx.x;
  const int row0 = blockIdx.x * 128;

  // stage W (Wt[n][k], 2048 16B-chunks -> 8 per thread)
#pragma unroll
  for (int i = 0; i < 8; ++i) {
    int chunk = i * 256 + tid;
    int r = chunk >> 4, cc = (chunk & 15) * 8;
    f16x8 v = *(const f16x8*)(Wt + (size_t)r * 128 + cc);
    *(f16x8*)(sW + swz(r, cc)) = v;
  }
  // stage X
#pragma unroll
  for (int i = 0; i < 8; ++i) {
    int chunk = i * 256 + tid;
    int r = chunk >> 4, cc = (chunk & 15) * 8;
    int grow = row0 + r;
    f16x8 v;
    if (SCALE) {
      const float* in = (const float*)inp;
      float4 v0 = {0, 0, 0, 0}, v1 = {0, 0, 0, 0};
      float s = 0.f;
      if (grow < NN) {
        v0 = *(const float4*)(in + (size_t)grow * DD + cc);
        v1 = *(const float4*)(in + (size_t)grow * DD + cc + 4);
        s = rsq_o[grow];
      }
      v[0] = (f16)(v0.x * s); v[1] = (f16)(v0.y * s);
      v[2] = (f16)(v0.z * s); v[3] = (f16)(v0.w * s);
      v[4] = (f16)(v1.x * s); v[5] = (f16)(v1.y * s);
      v[6] = (f16)(v1.z * s); v[7] = (f16)(v1.w * s);
    } else {
      const f16* in = (const f16*)inp;
      if (grow < NN) v = *(const f16x8*)(in + (size_t)grow * DD + cc);
      else { f16x8 z = {}; v = z; }
    }
    *(f16x8*)(sX + swz(r, cc)) = v;
  }
  __syncthreads();

  const int wv = tid >> 6, lane = tid & 63;
  const int am = lane & 31;   // m (A) / n (B) / col (C)
  const int kg = lane >> 5;   // k-group
  f32x16 acc[4];
#pragma unroll
  for (int ct = 0; ct < 4; ++ct)
#pragma unroll
    for (int q = 0; q < 16; ++q) acc[ct][q] = 0.f;

  const int ar = wv * 32 + am;
#pragma unroll
  for (int ks = 0; ks < 8; ++ks) {
    const int kc = ks * 16 + kg * 8;
    f16x8 af = *(const f16x8*)(sX + swz(ar, kc));
#pragma unroll
    for (int ct = 0; ct < 4; ++ct) {
      f16x8 bf = *(const f16x8*)(sW + swz(ct * 32 + am, kc));
      acc[ct] = __builtin_amdgcn_mfma_f32_32x32x16_f16(af, bf, acc[ct], 0, 0, 0);
    }
  }

#pragma unroll
  for (int ct = 0; ct < 4; ++ct) {
#pragma unroll
    for (int reg = 0; reg < 16; ++reg) {
      int trow = (reg & 3) + 8 * (reg >> 2) + 4 * kg;
      int grow = row0 + wv * 32 + trow;
      if (grow < NN) out[(size_t)grow * DD + ct * 32 + am] = (f16)acc[ct][reg];
    }
  }
}

// ---------------------------------------------------------------- gather (fp16 xw rows, fp32 accum)
// PRE: write relu(LN(h))*rsq_o as fp16 (next conv input). !PRE: write raw h fp32.
template <bool PRE>
__global__ __launch_bounds__(256) void k_gather(const f16* __restrict__ xw,
                                                const int* __restrict__ colx,
                                                const int* __restrict__ rowp,
                                                const float* __restrict__ rsq_i,
                                                const float* __restrict__ bias,
                                                const float* __restrict__ resid,
                                                const float* __restrict__ rsq_o,
                                                const float* __restrict__ g,
                                                const float* __restrict__ bb,
                                                void* __restrict__ outp) {
  const int wave = (blockIdx.x * 256 + threadIdx.x) >> 6;
  const int lane = threadIdx.x & 63;
  const int half = lane >> 5;
  const int l32 = lane & 31;
  if (wave >= NN) return;
  const int beg = rowp[wave], end = rowp[wave + 1];
  float4 a0 = {0, 0, 0, 0}, a1 = {0, 0, 0, 0}, a2 = {0, 0, 0, 0}, a3 = {0, 0, 0, 0};
  int e = beg + half;
  for (; e + 6 < end; e += 8) {
    int c0 = colx[e], c1 = colx[e + 2], c2 = colx[e + 4], c3 = colx[e + 6];
    f16x4 v0 = *(const f16x4*)(xw + (size_t)c0 * DD + l32 * 4);
    f16x4 v1 = *(const f16x4*)(xw + (size_t)c1 * DD + l32 * 4);
    f16x4 v2 = *(const f16x4*)(xw + (size_t)c2 * DD + l32 * 4);
    f16x4 v3 = *(const f16x4*)(xw + (size_t)c3 * DD + l32 * 4);
    a0.x += (float)v0[0]; a0.y += (float)v0[1]; a0.z += (float)v0[2]; a0.w += (float)v0[3];
    a1.x += (float)v1[0]; a1.y += (float)v1[1]; a1.z += (float)v1[2]; a1.w += (float)v1[3];
    a2.x += (float)v2[0]; a2.y += (float)v2[1]; a2.z += (float)v2[2]; a2.w += (float)v2[3];
    a3.x += (float)v3[0]; a3.y += (float)v3[1]; a3.z += (float)v3[2]; a3.w += (float)v3[3];
  }
  for (; e < end; e += 2) {
    int c = colx[e];
    f16x4 v = *(const f16x4*)(xw + (size_t)c * DD + l32 * 4);
    a0.x += (float)v[0]; a0.y += (float)v[1]; a0.z += (float)v[2]; a0.w += (float)v[3];
  }
  a0.x += a1.x + a2.x + a3.x;
  a0.y += a1.y + a2.y + a3.y;
  a0.z += a1.z + a2.z + a3.z;
  a0.w += a1.w + a2.w + a3.w;
  a0.x += __shfl_xor(a0.x, 32);
  a0.y += __shfl_xor(a0.y, 32);
  a0.z += __shfl_xor(a0.z, 32);
  a0.w += __shfl_xor(a0.w, 32);

  const float r = rsq_i[wave];
  float4 bv = *(const float4*)(bias + l32 * 4);
  float4 rf = *(const float4*)(resid + (size_t)wave * DD + l32 * 4);
  float4 o;
  o.x = a0.x * r + bv.x + RESC * rf.x;
  o.y = a0.y * r + bv.y + RESC * rf.y;
  o.z = a0.z * r + bv.z + RESC * rf.z;
  o.w = a0.w * r + bv.w + RESC * rf.w;

  if (PRE) {
    float s = o.x + o.y + o.z + o.w;
    float q = o.x * o.x + o.y * o.y + o.z * o.z + o.w * o.w;
#pragma unroll
    for (int off = 1; off < 32; off <<= 1) {
      s += __shfl_xor(s, off);
      q += __shfl_xor(q, off);
    }
    float mu = s * (1.f / 128.f);
    float var = q * (1.f / 128.f) - mu * mu;
    float rs = rsqrtf(var + EPSL);
    float sc = rsq_o[wave];
    float4 gv = *(const float4*)(g + l32 * 4);
    float4 lv = *(const float4*)(bb + l32 * 4);
    o.x = fmaxf((o.x - mu) * rs * gv.x + lv.x, 0.f) * sc;
    o.y = fmaxf((o.y - mu) * rs * gv.y + lv.y, 0.f) * sc;
    o.z = fmaxf((o.z - mu) * rs * gv.z + lv.z, 0.f) * sc;
    o.w = fmaxf((o.w - mu) * rs * gv.w + lv.w, 0.f) * sc;
    if (half == 0) {
      f16x4 o4;
      o4[0] = (f16)o.x; o4[1] = (f16)o.y; o4[2] = (f16)o.z; o4[3] = (f16)o.w;
      *(f16x4*)((f16*)outp + (size_t)wave * DD + l32 * 4) = o4;
    }
  } else {
    if (half == 0) *(float4*)((float*)outp + (size_t)wave * DD + l32 * 4) = o;
  }
}

// ---------------------------------------------------------------- launcher
extern "C" void kernel_launch(void* const* d_in, const int* in_sizes, int n_in,
                              void* d_out, int out_size, void* d_ws, size_t ws_size,
                              hipStream_t stream) {
  const int* src = (const int*)d_in[0];
  const int* dst = (const int*)d_in[1];
  const float* in_feat = (const float*)d_in[2];
  const float* W1 = (const float*)d_in[3];
  const float* b1 = (const float*)d_in[4];
  const float* W2 = (const float*)d_in[5];
  const float* b2 = (const float*)d_in[6];
  const float* g1 = (const float*)d_in[7];
  const float* lb1 = (const float*)d_in[8];
  const float* g2 = (const float*)d_in[9];
  const float* lb2 = (const float*)d_in[10];
  const int E = in_sizes[0];

  char* p = (char*)d_ws;
  auto alloc = [&](size_t bytes) {
    char* q = p;
    p += (bytes + 255) & ~(size_t)255;
    return q;
  };
  f16*   xw    = (f16*)alloc((size_t)NN * DD * 2);  // 25.6 MB (aliases gpairs 12.8 MB)
  f16*   hb    = (f16*)alloc((size_t)NN * DD * 2);
  float* rsq_o = (float*)alloc((size_t)NN * 4);
  float* rsq_i = (float*)alloc((size_t)NN * 4);
  int*   dego  = (int*)alloc((size_t)NN * 4);
  int*   rowp  = (int*)alloc((size_t)(NN + 1) * 4);
  int*   colx  = (int*)alloc((size_t)E * 4);
  int*   bsum  = (int*)alloc((size_t)NBKT * 4);
  int*   bpre  = (int*)alloc((size_t)NBKT * 4);
  int*   bcur  = (int*)alloc((size_t)NBKT * 4);
  f16*   Wt1   = (f16*)alloc((size_t)DD * DD * 2);
  f16*   Wt2   = (f16*)alloc((size_t)DD * DD * 2);
  if ((size_t)(p - (char*)d_ws) > ws_size) return;
  int2* gpairs = (int2*)xw;  // consumed by k_binB before gemm1 writes xw

  hipMemsetAsync(dego, 0, (size_t)NN * 4, stream);
  hipMemsetAsync(bsum, 0, (size_t)NBKT * 4, stream);

  const int eb = (E + 4095) / 4096;
  k_hist<<<eb, 256, 0, stream>>>(src, dst, dego, bsum, E);
  k_scan2<<<1, 128, 0, stream>>>(bsum, bpre, bcur);
  k_prep<<<(NN + 255) / 256, 256, 0, stream>>>(dego, rsq_o);
  k_wprep<<<64, 256, 0, stream>>>(W1, Wt1);
  k_wprep<<<64, 256, 0, stream>>>(W2, Wt2);
  k_binA<<<eb, 256, 0, stream>>>(src, dst, bcur, gpairs, E);
  k_binB<<<NBKT, 256, 0, stream>>>(gpairs, bpre, bsum, rowp, rsq_i, colx, E);

  const int gblk = (NN + 127) / 128;
  const int agblk = (NN * 64 + 255) / 256;
  const size_t ldsb = 65536;

  // conv1
  k_gemm16<true><<<gblk, 256, ldsb, stream>>>(in_feat, Wt1, rsq_o, xw);
  k_gather<true><<<agblk, 256, 0, stream>>>(xw, colx, rowp, rsq_i, b1, in_feat, rsq_o, g1, lb1, hb);
  // conv2
  k_gemm16<false><<<gblk, 256, ldsb, stream>>>(hb, Wt2, rsq_o, xw);
  k_gather<true><<<agblk, 256, 0, stream>>>(xw, colx, rowp, rsq_i, b2, in_feat, rsq_o, g2, lb2, hb);
  // conv3
  k_gemm16<false><<<gblk, 256, ldsb, stream>>>(hb, Wt2, rsq_o, xw);
  k_gather<false><<<agblk, 256, 0, stream>>>(xw, colx, rowp, rsq_i, b2, in_feat, rsq_o, nullptr, nullptr, d_out);
}